// Round 8
// baseline (197.685 us; speedup 1.0000x reference)
//
#include <hip/hip_runtime.h>
#include <stdint.h>

#define Bn 256
#define Tn 50
#define Mn 20
#define En 128
#define G3 384
#define MT 64
#define LDA 132

typedef float f32x4 __attribute__((ext_vector_type(4)));

__device__ __forceinline__ float sigmoidf(float x) {
    return 1.0f / (1.0f + __expf(-x));
}
__device__ __forceinline__ float tanh_safe(float a) {
    float ax = fabsf(a);
    float e2 = __expf(-2.0f * ax);
    return copysignf((1.0f - e2) / (1.0f + e2), a);
}

// Force a value into an AGPR (architecturally register-resident: an asm-def'd
// AGPR cannot be rematerialized from memory or spilled behind our back).
__device__ __forceinline__ float agpr_put(float v) {
    float a;
    asm volatile("v_accvgpr_write_b32 %0, %1" : "=a"(a) : "v"(v));
    return a;
}
__device__ __forceinline__ float agpr_get(const float& a) {
    float v;
    asm volatile("v_accvgpr_read_b32 %0, %1" : "=v"(v) : "a"(a));
    return v;
}

// ---------------------------------------------------------------------------
// Kernel 1: basket-mean gather -> ub [B*T][128]  (stored in d_out region)
// ---------------------------------------------------------------------------
__global__ __launch_bounds__(256) void gather_kernel(
    const int*   __restrict__ item_ids,
    const int*   __restrict__ basket_sizes,
    const float* __restrict__ emb,
    float* __restrict__ ub)
{
    const int bt   = blockIdx.x * 8 + (threadIdx.x >> 5);
    const int lane = threadIdx.x & 31;
    const int* ids = item_ids + (size_t)bt * Mn;
    float ax = 0.f, ay = 0.f, az = 0.f, aw = 0.f;
    #pragma unroll
    for (int m = 0; m < Mn; ++m) {
        const float4 v = *(const float4*)(emb + (size_t)ids[m] * En + lane * 4);
        ax += v.x; ay += v.y; az += v.z; aw += v.w;
    }
    const float inv = 1.0f / (float)basket_sizes[bt];
    *(float4*)(ub + (size_t)bt * En + lane * 4) =
        make_float4(ax * inv, ay * inv, az * inv, aw * inv);
}

// ---------------------------------------------------------------------------
// Kernel 2: xg = ub @ W_ih^T + b_ih.  1200 blocks (200 M x 6 N); 4x4 tile.
// ---------------------------------------------------------------------------
__global__ __launch_bounds__(256, 2) void gemm_kernel(
    const float* __restrict__ ub,
    const float* __restrict__ W_ih,
    const float* __restrict__ b_ih,
    float* __restrict__ xg)
{
    __shared__ float A[MT][LDA];
    __shared__ float Bt[64][LDA];

    const int tid  = threadIdx.x;
    const int mt   = blockIdx.x / 6;
    const int nc   = blockIdx.x % 6;
    const int row0 = mt * MT;
    const int col0 = nc * 64;

    {
        const int r = tid >> 2, seg = tid & 3;
        const float4* srcA = (const float4*)(ub + (size_t)(row0 + r) * En + seg * 32);
        const float4* srcB = (const float4*)(W_ih + (size_t)(col0 + r) * En + seg * 32);
        float4* dstA = (float4*)&A[r][seg * 32];
        float4* dstB = (float4*)&Bt[r][seg * 32];
        #pragma unroll
        for (int c = 0; c < 8; ++c) { dstA[c] = srcA[c]; dstB[c] = srcB[c]; }
    }
    __syncthreads();

    const int tx = tid & 15;
    const int ty = tid >> 4;

    float acc[4][4];
    #pragma unroll
    for (int i = 0; i < 4; ++i)
        #pragma unroll
        for (int u = 0; u < 4; ++u) acc[i][u] = 0.0f;

    #pragma unroll 4
    for (int k4 = 0; k4 < 32; ++k4) {
        const float4 av[4] = {
            *(const float4*)&A[ty +  0][k4*4], *(const float4*)&A[ty + 16][k4*4],
            *(const float4*)&A[ty + 32][k4*4], *(const float4*)&A[ty + 48][k4*4]};
        const float4 bv[4] = {
            *(const float4*)&Bt[tx +  0][k4*4], *(const float4*)&Bt[tx + 16][k4*4],
            *(const float4*)&Bt[tx + 32][k4*4], *(const float4*)&Bt[tx + 48][k4*4]};
        #pragma unroll
        for (int i = 0; i < 4; ++i)
            #pragma unroll
            for (int u = 0; u < 4; ++u) {
                acc[i][u] = fmaf(av[i].x, bv[u].x, acc[i][u]);
                acc[i][u] = fmaf(av[i].y, bv[u].y, acc[i][u]);
                acc[i][u] = fmaf(av[i].z, bv[u].z, acc[i][u]);
                acc[i][u] = fmaf(av[i].w, bv[u].w, acc[i][u]);
            }
    }

    float bias[4];
    #pragma unroll
    for (int u = 0; u < 4; ++u) bias[u] = b_ih[col0 + tx + 16*u];
    #pragma unroll
    for (int i = 0; i < 4; ++i) {
        const size_t rowoff = (size_t)(row0 + ty + 16*i) * G3;
        #pragma unroll
        for (int u = 0; u < 4; ++u)
            xg[rowoff + col0 + tx + 16*u] = acc[i][u] + bias[u];
    }
}

// ---------------------------------------------------------------------------
// Kernel 3: sequential GRU. 256 blocks x 512 threads (8 waves, 2/SIMD).
// Thread (j=tid>>2 in [0,128), q=tid&3) owns gate rows {j,128+j,256+j},
// cols [q*32,q*32+32) = 96 weights.
//
// ROUND-8: eight compiler-route variants never achieved weight residency
// (VGPR 40..132, streams from L2 or spills to scratch; both = the invariant
// ~2100 cyc/step floor, since 196 KB/step through ANY memory tier is
// 1500-3000 cyc and only the register file has the bandwidth).  Now forced
// at ISA level: weights written ONCE into 96 AGPRs per thread via
// v_accvgpr_write_b32 with "a" constraints — an asm-def'd AGPR value cannot
// be remat'd from memory or silently spilled.  In-loop: v_accvgpr_read +
// fmaf (conservative; direct AGPR-src v_fmac is next if this lands).
// Budget: 96 AGPR + ~110 VGPR < 256 at waves_per_eu(2,2) (2 waves/SIMD).
// Success signatures: VGPR_Count >= ~200, WRITE_SIZE back to 6528.
// ---------------------------------------------------------------------------
__global__ __launch_bounds__(512)
__attribute__((amdgpu_waves_per_eu(2, 2)))
void gru_kernel(
    const int*   __restrict__ lengths,
    const float* __restrict__ W_hh,
    const float* __restrict__ b_hh,
    const float* __restrict__ h0,
    const float* __restrict__ xg,
    float* __restrict__ out_dyn,
    float* __restrict__ out_h)
{
    extern __shared__ float smem[];
    float* hs  = smem;          // [2][En] double-buffered h
    float* sxg = smem + 2 * En; // [Tn*G3] staged x-gates (76.8 KB)

    const int tid = threadIdx.x;
    const int b   = blockIdx.x;
    const int j   = tid >> 2;        // [0,128)
    const int q   = tid & 3;         // [0,4) — the DPP quad

    const int len = lengths[b];
    const float* xgb = xg + (size_t)b * Tn * G3;
    float* outb = out_dyn + (size_t)b * Tn * En;

    // ---- one-time stage: xg[b] -> LDS (simple coalesced float4 loop) ----
    {
        const float4* src = (const float4*)xgb;
        float4* dst = (float4*)sxg;
        const int nv4 = len * (G3 / 4);      // <= 4800
        for (int i = tid; i < nv4; i += 512) dst[i] = src[i];
    }

    // ---- weights -> AGPRs (once).  Rotation (c+2q)&7 applied identically
    // at load and at h-read so the 4 q-groups hit disjoint LDS bank quads.
    float wa0[32], wa1[32], wa2[32];   // AGPR-resident (asm-def'd)
    {
        const f32x4* p0 = (const f32x4*)(W_hh + (size_t)(0*En + j) * En + q * 32);
        const f32x4* p1 = (const f32x4*)(W_hh + (size_t)(1*En + j) * En + q * 32);
        const f32x4* p2 = (const f32x4*)(W_hh + (size_t)(2*En + j) * En + q * 32);
        #pragma unroll
        for (int c = 0; c < 8; ++c) {
            const int cc = (c + 2*q) & 7;
            const f32x4 v0 = p0[cc], v1 = p1[cc], v2 = p2[cc];
            wa0[4*c+0] = agpr_put(v0.x); wa0[4*c+1] = agpr_put(v0.y);
            wa0[4*c+2] = agpr_put(v0.z); wa0[4*c+3] = agpr_put(v0.w);
            wa1[4*c+0] = agpr_put(v1.x); wa1[4*c+1] = agpr_put(v1.y);
            wa1[4*c+2] = agpr_put(v1.z); wa1[4*c+3] = agpr_put(v1.w);
            wa2[4*c+0] = agpr_put(v2.x); wa2[4*c+1] = agpr_put(v2.y);
            wa2[4*c+2] = agpr_put(v2.z); wa2[4*c+3] = agpr_put(v2.w);
        }
    }

    const float br = b_hh[j], bz = b_hh[En + j], bn = b_hh[2*En + j];
    float hprev = h0[(size_t)b * En + j];
    if (q == 0) hs[j] = hprev;
    __syncthreads();   // one-time full drain: staging + hs[0] visible

    int cur = 0;
    for (int t = 0; t < len; ++t) {
        // x-gates from LDS — issued early, consumed after the dots
        const float x0r = sxg[t*G3 + j];
        const float x0z = sxg[t*G3 + En + j];
        const float x0n = sxg[t*G3 + 2*En + j];

        // partial dots over this thread's 32-col K-slice; weights come from
        // AGPRs (accvgpr_read), h from LDS (rotated walk, conflict-free).
        const f32x4* h4 = ((const f32x4*)(hs + cur * En)) + q * 8;
        float a0 = 0.f, a1 = 0.f, a2 = 0.f;
        #pragma unroll
        for (int c = 0; c < 8; ++c) {
            const f32x4 hv = h4[(c + 2*q) & 7];
            a0 = fmaf(agpr_get(wa0[4*c+0]), hv.x, a0);
            a0 = fmaf(agpr_get(wa0[4*c+1]), hv.y, a0);
            a0 = fmaf(agpr_get(wa0[4*c+2]), hv.z, a0);
            a0 = fmaf(agpr_get(wa0[4*c+3]), hv.w, a0);
            a1 = fmaf(agpr_get(wa1[4*c+0]), hv.x, a1);
            a1 = fmaf(agpr_get(wa1[4*c+1]), hv.y, a1);
            a1 = fmaf(agpr_get(wa1[4*c+2]), hv.z, a1);
            a1 = fmaf(agpr_get(wa1[4*c+3]), hv.w, a1);
            a2 = fmaf(agpr_get(wa2[4*c+0]), hv.x, a2);
            a2 = fmaf(agpr_get(wa2[4*c+1]), hv.y, a2);
            a2 = fmaf(agpr_get(wa2[4*c+2]), hv.z, a2);
            a2 = fmaf(agpr_get(wa2[4*c+3]), hv.w, a2);
        }

        // in-quad butterfly reduce over q — DPP, pure VALU
        {
            int t0 = __builtin_amdgcn_update_dpp(0, __float_as_int(a0),
                                                 0xB1, 0xF, 0xF, true);
            a0 += __int_as_float(t0);
            t0 = __builtin_amdgcn_update_dpp(0, __float_as_int(a0),
                                             0x4E, 0xF, 0xF, true);
            a0 += __int_as_float(t0);
            int u0 = __builtin_amdgcn_update_dpp(0, __float_as_int(a1),
                                                 0xB1, 0xF, 0xF, true);
            a1 += __int_as_float(u0);
            u0 = __builtin_amdgcn_update_dpp(0, __float_as_int(a1),
                                             0x4E, 0xF, 0xF, true);
            a1 += __int_as_float(u0);
            int v0 = __builtin_amdgcn_update_dpp(0, __float_as_int(a2),
                                                 0xB1, 0xF, 0xF, true);
            a2 += __int_as_float(v0);
            v0 = __builtin_amdgcn_update_dpp(0, __float_as_int(a2),
                                             0x4E, 0xF, 0xF, true);
            a2 += __int_as_float(v0);
        }

        // gates — computed redundantly by all 4 q-lanes
        const float r = sigmoidf(x0r + br + a0);
        const float z = sigmoidf(x0z + bz + a1);
        const float n = tanh_safe(x0n + r * (bn + a2));
        const float hnew = (1.0f - z) * n + z * hprev;

        if (q == 0) {
            hs[(cur ^ 1) * En + j] = hnew;  // write the OTHER buffer
            outb[t*En + j] = hnew;          // fire-and-forget store
        }
        // Raw barrier: drain LDS only; global stores stay in flight.
        asm volatile("s_waitcnt lgkmcnt(0)" ::: "memory");
        __builtin_amdgcn_s_barrier();
        __builtin_amdgcn_sched_barrier(0);

        hprev = hnew;
        cur ^= 1;
    }

    if (q == 0) {
        for (int t = len; t < Tn; ++t) outb[t*En + j] = 0.0f;
        out_h[(size_t)b * En + j] = hprev;
    }
}

extern "C" void kernel_launch(void* const* d_in, const int* in_sizes, int n_in,
                              void* d_out, int out_size, void* d_ws, size_t ws_size,
                              hipStream_t stream) {
    const int*   item_ids     = (const int*)d_in[0];
    const int*   basket_sizes = (const int*)d_in[1];
    const int*   lengths      = (const int*)d_in[2];
    const float* emb          = (const float*)d_in[3];
    const float* W_ih         = (const float*)d_in[4];
    const float* W_hh         = (const float*)d_in[5];
    const float* b_ih         = (const float*)d_in[6];
    const float* b_hh         = (const float*)d_in[7];
    const float* h0           = (const float*)d_in[8];
    float* out = (float*)d_out;
    float* xg  = (float*)d_ws;   // 19.7 MB
    float* ub  = out;            // reuse out_dyn region; overwritten by gru later

    // Allow >64KB dynamic LDS for gru_kernel (HW max 160 KB on gfx950).
    static bool lds_attr_set = false;
    if (!lds_attr_set) {
        (void)hipFuncSetAttribute((const void*)gru_kernel,
                                  hipFuncAttributeMaxDynamicSharedMemorySize,
                                  (2 * En + Tn * G3) * (int)sizeof(float));
        lds_attr_set = true;
    }

    gather_kernel<<<(Bn * Tn) / 8, 256, 0, stream>>>(item_ids, basket_sizes, emb, ub);
    gemm_kernel<<<1200, 256, 0, stream>>>(ub, W_ih, b_ih, xg);
    gru_kernel<<<Bn, 512, (2 * En + Tn * G3) * sizeof(float), stream>>>(
        lengths, W_hh, b_hh, h0, xg, out, out + (size_t)Bn * Tn * En);
}

// Round 9
// 192.995 us; speedup vs baseline: 1.0243x; 1.0243x over previous
//
#include <hip/hip_runtime.h>
#include <stdint.h>

#define Bn 256
#define Tn 50
#define Mn 20
#define En 128
#define G3 384
#define MT 64
#define LDA 132

typedef float f32x4 __attribute__((ext_vector_type(4)));

__device__ __forceinline__ float sigmoidf(float x) {
    return 1.0f / (1.0f + __expf(-x));
}
__device__ __forceinline__ float tanh_safe(float a) {
    float ax = fabsf(a);
    float e2 = __expf(-2.0f * ax);
    return copysignf((1.0f - e2) / (1.0f + e2), a);
}

// Force a value into an AGPR (architecturally register-resident: an asm-def'd
// AGPR cannot be rematerialized from memory or spilled behind our back).
__device__ __forceinline__ float agpr_put(float v) {
    float a;
    asm volatile("v_accvgpr_write_b32 %0, %1" : "=a"(a) : "v"(v));
    return a;
}
__device__ __forceinline__ float agpr_get(const float& a) {
    float v;
    asm volatile("v_accvgpr_read_b32 %0, %1" : "=v"(v) : "a"(a));
    return v;
}

// ---------------------------------------------------------------------------
// Kernel 1: basket-mean gather -> ub [B*T][128]  (stored in d_out region)
// ---------------------------------------------------------------------------
__global__ __launch_bounds__(256) void gather_kernel(
    const int*   __restrict__ item_ids,
    const int*   __restrict__ basket_sizes,
    const float* __restrict__ emb,
    float* __restrict__ ub)
{
    const int bt   = blockIdx.x * 8 + (threadIdx.x >> 5);
    const int lane = threadIdx.x & 31;
    const int* ids = item_ids + (size_t)bt * Mn;
    float ax = 0.f, ay = 0.f, az = 0.f, aw = 0.f;
    #pragma unroll
    for (int m = 0; m < Mn; ++m) {
        const float4 v = *(const float4*)(emb + (size_t)ids[m] * En + lane * 4);
        ax += v.x; ay += v.y; az += v.z; aw += v.w;
    }
    const float inv = 1.0f / (float)basket_sizes[bt];
    *(float4*)(ub + (size_t)bt * En + lane * 4) =
        make_float4(ax * inv, ay * inv, az * inv, aw * inv);
}

// ---------------------------------------------------------------------------
// Kernel 2: xg = ub @ W_ih^T + b_ih.  1200 blocks (200 M x 6 N); 4x4 tile.
// ---------------------------------------------------------------------------
__global__ __launch_bounds__(256, 2) void gemm_kernel(
    const float* __restrict__ ub,
    const float* __restrict__ W_ih,
    const float* __restrict__ b_ih,
    float* __restrict__ xg)
{
    __shared__ float A[MT][LDA];
    __shared__ float Bt[64][LDA];

    const int tid  = threadIdx.x;
    const int mt   = blockIdx.x / 6;
    const int nc   = blockIdx.x % 6;
    const int row0 = mt * MT;
    const int col0 = nc * 64;

    {
        const int r = tid >> 2, seg = tid & 3;
        const float4* srcA = (const float4*)(ub + (size_t)(row0 + r) * En + seg * 32);
        const float4* srcB = (const float4*)(W_ih + (size_t)(col0 + r) * En + seg * 32);
        float4* dstA = (float4*)&A[r][seg * 32];
        float4* dstB = (float4*)&Bt[r][seg * 32];
        #pragma unroll
        for (int c = 0; c < 8; ++c) { dstA[c] = srcA[c]; dstB[c] = srcB[c]; }
    }
    __syncthreads();

    const int tx = tid & 15;
    const int ty = tid >> 4;

    float acc[4][4];
    #pragma unroll
    for (int i = 0; i < 4; ++i)
        #pragma unroll
        for (int u = 0; u < 4; ++u) acc[i][u] = 0.0f;

    #pragma unroll 4
    for (int k4 = 0; k4 < 32; ++k4) {
        const float4 av[4] = {
            *(const float4*)&A[ty +  0][k4*4], *(const float4*)&A[ty + 16][k4*4],
            *(const float4*)&A[ty + 32][k4*4], *(const float4*)&A[ty + 48][k4*4]};
        const float4 bv[4] = {
            *(const float4*)&Bt[tx +  0][k4*4], *(const float4*)&Bt[tx + 16][k4*4],
            *(const float4*)&Bt[tx + 32][k4*4], *(const float4*)&Bt[tx + 48][k4*4]};
        #pragma unroll
        for (int i = 0; i < 4; ++i)
            #pragma unroll
            for (int u = 0; u < 4; ++u) {
                acc[i][u] = fmaf(av[i].x, bv[u].x, acc[i][u]);
                acc[i][u] = fmaf(av[i].y, bv[u].y, acc[i][u]);
                acc[i][u] = fmaf(av[i].z, bv[u].z, acc[i][u]);
                acc[i][u] = fmaf(av[i].w, bv[u].w, acc[i][u]);
            }
    }

    float bias[4];
    #pragma unroll
    for (int u = 0; u < 4; ++u) bias[u] = b_ih[col0 + tx + 16*u];
    #pragma unroll
    for (int i = 0; i < 4; ++i) {
        const size_t rowoff = (size_t)(row0 + ty + 16*i) * G3;
        #pragma unroll
        for (int u = 0; u < 4; ++u)
            xg[rowoff + col0 + tx + 16*u] = acc[i][u] + bias[u];
    }
}

// ---------------------------------------------------------------------------
// Kernel 3: sequential GRU. 256 blocks x 512 threads (8 waves, 2/SIMD).
// Thread (j=tid>>2 in [0,128), q=tid&3) owns gate rows {j,128+j,256+j},
// cols [q*32,q*32+32) = 96 weights, AGPR-resident.
//
// ROUND-9: r8 proved AGPR residency works (WRITE_SIZE back to 6528, no
// spill, VMEM weight stream gone) but regressed because the 288 interleaved
// `asm volatile` read/fma pairs are mutually ORDERED -> a serial dependency
// chain (~2300 cyc/step stall).  Fix is scheduling, not storage: batch all
// 96 accvgpr_reads back-to-back at the top of the step (independent ->
// pipelined 2-cyc issue, latency overlapped), then consume via f32x4 vector
// accumulation (chance of v_pk_fma_f32, halving FMA issue) + 9-op
// horizontal add.  Budget: 96 AGPR + ~200 VGPR < 512/wave at 2 waves/SIMD.
// ---------------------------------------------------------------------------
__global__ __launch_bounds__(512)
__attribute__((amdgpu_waves_per_eu(2, 2)))
void gru_kernel(
    const int*   __restrict__ lengths,
    const float* __restrict__ W_hh,
    const float* __restrict__ b_hh,
    const float* __restrict__ h0,
    const float* __restrict__ xg,
    float* __restrict__ out_dyn,
    float* __restrict__ out_h)
{
    extern __shared__ float smem[];
    float* hs  = smem;          // [2][En] double-buffered h
    float* sxg = smem + 2 * En; // [Tn*G3] staged x-gates (76.8 KB)

    const int tid = threadIdx.x;
    const int b   = blockIdx.x;
    const int j   = tid >> 2;        // [0,128)
    const int q   = tid & 3;         // [0,4) — the DPP quad

    const int len = lengths[b];
    const float* xgb = xg + (size_t)b * Tn * G3;
    float* outb = out_dyn + (size_t)b * Tn * En;

    // ---- one-time stage: xg[b] -> LDS (simple coalesced float4 loop) ----
    {
        const float4* src = (const float4*)xgb;
        float4* dst = (float4*)sxg;
        const int nv4 = len * (G3 / 4);      // <= 4800
        for (int i = tid; i < nv4; i += 512) dst[i] = src[i];
    }

    // ---- weights -> AGPRs (once).  Rotation (c+2q)&7 applied identically
    // at load and at h-read so the 4 q-groups hit disjoint LDS bank quads.
    float wa0[32], wa1[32], wa2[32];   // AGPR-resident (asm-def'd)
    {
        const f32x4* p0 = (const f32x4*)(W_hh + (size_t)(0*En + j) * En + q * 32);
        const f32x4* p1 = (const f32x4*)(W_hh + (size_t)(1*En + j) * En + q * 32);
        const f32x4* p2 = (const f32x4*)(W_hh + (size_t)(2*En + j) * En + q * 32);
        #pragma unroll
        for (int c = 0; c < 8; ++c) {
            const int cc = (c + 2*q) & 7;
            const f32x4 v0 = p0[cc], v1 = p1[cc], v2 = p2[cc];
            wa0[4*c+0] = agpr_put(v0.x); wa0[4*c+1] = agpr_put(v0.y);
            wa0[4*c+2] = agpr_put(v0.z); wa0[4*c+3] = agpr_put(v0.w);
            wa1[4*c+0] = agpr_put(v1.x); wa1[4*c+1] = agpr_put(v1.y);
            wa1[4*c+2] = agpr_put(v1.z); wa1[4*c+3] = agpr_put(v1.w);
            wa2[4*c+0] = agpr_put(v2.x); wa2[4*c+1] = agpr_put(v2.y);
            wa2[4*c+2] = agpr_put(v2.z); wa2[4*c+3] = agpr_put(v2.w);
        }
    }

    const float br = b_hh[j], bz = b_hh[En + j], bn = b_hh[2*En + j];
    float hprev = h0[(size_t)b * En + j];
    if (q == 0) hs[j] = hprev;
    __syncthreads();   // one-time full drain: staging + hs[0] visible

    int cur = 0;
    for (int t = 0; t < len; ++t) {
        // x-gates from LDS — issued early, consumed after the dots
        const float x0r = sxg[t*G3 + j];
        const float x0z = sxg[t*G3 + En + j];
        const float x0n = sxg[t*G3 + 2*En + j];

        // ---- batched AGPR readback: 96 independent reads, back-to-back
        // issue (volatile keeps them ordered among themselves = batched at
        // the top; latencies overlap since there are no data deps).
        float rw0[32], rw1[32], rw2[32];
        #pragma unroll
        for (int c = 0; c < 32; ++c) {
            rw0[c] = agpr_get(wa0[c]);
            rw1[c] = agpr_get(wa1[c]);
            rw2[c] = agpr_get(wa2[c]);
        }

        // ---- vector accumulation over the 32-col K-slice (pk_fma-friendly)
        const f32x4* h4 = ((const f32x4*)(hs + cur * En)) + q * 8;
        f32x4 acc0 = {0.f, 0.f, 0.f, 0.f};
        f32x4 acc1 = {0.f, 0.f, 0.f, 0.f};
        f32x4 acc2 = {0.f, 0.f, 0.f, 0.f};
        #pragma unroll
        for (int c = 0; c < 8; ++c) {
            const f32x4 hv = h4[(c + 2*q) & 7];
            f32x4 w0v; w0v.x = rw0[4*c+0]; w0v.y = rw0[4*c+1];
                       w0v.z = rw0[4*c+2]; w0v.w = rw0[4*c+3];
            f32x4 w1v; w1v.x = rw1[4*c+0]; w1v.y = rw1[4*c+1];
                       w1v.z = rw1[4*c+2]; w1v.w = rw1[4*c+3];
            f32x4 w2v; w2v.x = rw2[4*c+0]; w2v.y = rw2[4*c+1];
                       w2v.z = rw2[4*c+2]; w2v.w = rw2[4*c+3];
            acc0 += w0v * hv;
            acc1 += w1v * hv;
            acc2 += w2v * hv;
        }
        float a0 = (acc0.x + acc0.y) + (acc0.z + acc0.w);
        float a1 = (acc1.x + acc1.y) + (acc1.z + acc1.w);
        float a2 = (acc2.x + acc2.y) + (acc2.z + acc2.w);

        // in-quad butterfly reduce over q — DPP, pure VALU
        {
            int t0 = __builtin_amdgcn_update_dpp(0, __float_as_int(a0),
                                                 0xB1, 0xF, 0xF, true);
            a0 += __int_as_float(t0);
            t0 = __builtin_amdgcn_update_dpp(0, __float_as_int(a0),
                                             0x4E, 0xF, 0xF, true);
            a0 += __int_as_float(t0);
            int u0 = __builtin_amdgcn_update_dpp(0, __float_as_int(a1),
                                                 0xB1, 0xF, 0xF, true);
            a1 += __int_as_float(u0);
            u0 = __builtin_amdgcn_update_dpp(0, __float_as_int(a1),
                                             0x4E, 0xF, 0xF, true);
            a1 += __int_as_float(u0);
            int v0 = __builtin_amdgcn_update_dpp(0, __float_as_int(a2),
                                                 0xB1, 0xF, 0xF, true);
            a2 += __int_as_float(v0);
            v0 = __builtin_amdgcn_update_dpp(0, __float_as_int(a2),
                                             0x4E, 0xF, 0xF, true);
            a2 += __int_as_float(v0);
        }

        // gates — computed redundantly by all 4 q-lanes
        const float r = sigmoidf(x0r + br + a0);
        const float z = sigmoidf(x0z + bz + a1);
        const float n = tanh_safe(x0n + r * (bn + a2));
        const float hnew = (1.0f - z) * n + z * hprev;

        if (q == 0) {
            hs[(cur ^ 1) * En + j] = hnew;  // write the OTHER buffer
            outb[t*En + j] = hnew;          // fire-and-forget store
        }
        // Raw barrier: drain LDS only; global stores stay in flight.
        asm volatile("s_waitcnt lgkmcnt(0)" ::: "memory");
        __builtin_amdgcn_s_barrier();
        __builtin_amdgcn_sched_barrier(0);

        hprev = hnew;
        cur ^= 1;
    }

    if (q == 0) {
        for (int t = len; t < Tn; ++t) outb[t*En + j] = 0.0f;
        out_h[(size_t)b * En + j] = hprev;
    }
}

extern "C" void kernel_launch(void* const* d_in, const int* in_sizes, int n_in,
                              void* d_out, int out_size, void* d_ws, size_t ws_size,
                              hipStream_t stream) {
    const int*   item_ids     = (const int*)d_in[0];
    const int*   basket_sizes = (const int*)d_in[1];
    const int*   lengths      = (const int*)d_in[2];
    const float* emb          = (const float*)d_in[3];
    const float* W_ih         = (const float*)d_in[4];
    const float* W_hh         = (const float*)d_in[5];
    const float* b_ih         = (const float*)d_in[6];
    const float* b_hh         = (const float*)d_in[7];
    const float* h0           = (const float*)d_in[8];
    float* out = (float*)d_out;
    float* xg  = (float*)d_ws;   // 19.7 MB
    float* ub  = out;            // reuse out_dyn region; overwritten by gru later

    // Allow >64KB dynamic LDS for gru_kernel (HW max 160 KB on gfx950).
    static bool lds_attr_set = false;
    if (!lds_attr_set) {
        (void)hipFuncSetAttribute((const void*)gru_kernel,
                                  hipFuncAttributeMaxDynamicSharedMemorySize,
                                  (2 * En + Tn * G3) * (int)sizeof(float));
        lds_attr_set = true;
    }

    gather_kernel<<<(Bn * Tn) / 8, 256, 0, stream>>>(item_ids, basket_sizes, emb, ub);
    gemm_kernel<<<1200, 256, 0, stream>>>(ub, W_ih, b_ih, xg);
    gru_kernel<<<Bn, 512, (2 * En + Tn * G3) * sizeof(float), stream>>>(
        lengths, W_hh, b_hh, h0, xg, out, out + (size_t)Bn * Tn * En);
}